// Round 5
// baseline (240.105 us; speedup 1.0000x reference)
//
#include <hip/hip_runtime.h>

// VQ-VAE forward: N=131072 rows (D=64), K=512 codes.
// Outputs flat: [loss(1) | quantized_st(8388608, NCHW) | perplexity(1) | encodings(131072x512)]
//
// R5 theory (from R4: occupancy 22->41% but VALUBusy pinned ~33%, time flat): the k-loop is
// throttled by a shared per-CU resource = scalar-cache streaming of the embedding (each wave
// re-streams 64KB of s_loads per pass; 16 waves/CU thrash sK$). Fix: stage the whole 128KB
// table in LDS once per block; inner loop reads e-rows via wave-uniform ds_read_b128
// (same-address broadcast, conflict-free). 512 thr/block, 134KB LDS -> 1 block/CU,
// 2 waves/SIMD, 2 grid passes. Distance math bit-identical to R1-R4 (absmax was 0.0).

#define OFF_Q    1
#define OFF_PERP 8388609
#define OFF_ENC  8388610

__global__ __launch_bounds__(512) void vq_prep(const float* __restrict__ emb,
                                               float* __restrict__ Bk,
                                               unsigned* __restrict__ counts,
                                               unsigned long long* __restrict__ lossAcc) {
    int k = threadIdx.x;  // 512 threads, one per code
    const float4* e4 = reinterpret_cast<const float4*>(emb) + k * 16;
    float s = 0.f;
    #pragma unroll
    for (int i = 0; i < 16; ++i) {
        float4 v = e4[i];
        s += v.x * v.x + v.y * v.y + v.z * v.z + v.w * v.w;
    }
    Bk[k] = s;
    counts[k] = 0u;
    if (k == 0) *lossAcc = 0ull;
}

__global__ __launch_bounds__(512, 2) void vq_main(const float* __restrict__ in,
                                                  const float* __restrict__ emb,
                                                  const float* __restrict__ Bk,
                                                  unsigned* __restrict__ counts,
                                                  unsigned long long* __restrict__ lossAcc,
                                                  float* __restrict__ out) {
    __shared__ float tbl[32768];      // full embedding table, 128KB
    __shared__ float ldsBk[512];      // ||e_k||^2, 2KB
    __shared__ float sd[8][64];       // per-wave best distance
    __shared__ int   sk[8][64];       // per-wave best index

    const int tid  = (int)threadIdx.x;
    const int lane = tid & 63;
    const int wv   = tid >> 6;                                     // 0..7
    const int rg   = __builtin_amdgcn_readfirstlane(wv >> 1);      // row-group in block 0..3
    const int half = __builtin_amdgcn_readfirstlane(wv & 1);       // K-half (uniform)
    const int g    = (int)blockIdx.x * 4 + rg;                     // 0..2047 = b*64+h
    const int bb   = g >> 6;
    const int hh   = g & 63;
    const size_t inBase = (size_t)bb * 262144 + (size_t)hh * 64 + (size_t)lane;

    // ---- stage table + Bk into LDS (one-time, off critical path) ----
    {
        const float4* eg4 = reinterpret_cast<const float4*>(emb);
        float4* t4 = reinterpret_cast<float4*>(tbl);
        #pragma unroll
        for (int i = 0; i < 16; ++i) t4[tid + i * 512] = eg4[tid + i * 512];
        ldsBk[tid & 511] = Bk[tid & 511];
    }

    // ---- load this lane's row (overlaps staging), pin in VGPRs ----
    float x[64];
    #pragma unroll
    for (int c = 0; c < 64; ++c) x[c] = in[inBase + (size_t)c * 4096];
    #pragma unroll
    for (int i = 0; i < 64; ++i) asm volatile("" : "+v"(x[i]));

    // ||x||^2
    float a0 = 0.f, a1 = 0.f, a2 = 0.f, a3 = 0.f;
    #pragma unroll
    for (int c = 0; c < 64; c += 4) {
        a0 += x[c] * x[c];
        a1 += x[c + 1] * x[c + 1];
        a2 += x[c + 2] * x[c + 2];
        a3 += x[c + 3] * x[c + 3];
    }
    const float A = (a0 + a1) + (a2 + a3);

    __syncthreads();   // table staged

    // Zero-fill this wave's 16384-float region of group g's encodings slab,
    // paced one dword store per lane per iteration (256B/wave/iter).
    float* encZ = out + OFF_ENC + (size_t)g * 32768 + (size_t)half * 16384;

    const int kbase = half * 256;
    float bd = 3.4e38f;
    int   bk = kbase;

    for (int kk = 0; kk < 256; ++kk) {
        encZ[kk * 64 + lane] = 0.f;                 // paced zero-fill

        const int k = kbase + kk;                   // uniform -> LDS broadcast reads
        const float* __restrict__ tb = &tbl[k * 64];
        const float bkk = ldsBk[k];

        float c0 = 0.f, c1 = 0.f, c2 = 0.f, c3 = 0.f;
        #pragma unroll
        for (int d = 0; d < 64; d += 4) {
            float4 ev = *reinterpret_cast<const float4*>(&tb[d]);  // ds_read_b128 broadcast
            c0 += x[d]     * ev.x;
            c1 += x[d + 1] * ev.y;
            c2 += x[d + 2] * ev.z;
            c3 += x[d + 3] * ev.w;
        }
        float dot  = (c0 + c1) + (c2 + c3);
        float dist = (A + bkk) - 2.0f * dot;        // reference op order
        if (dist < bd) { bd = dist; bk = k; }       // strict < = first-min
    }

    sd[wv][lane] = bd;
    sk[wv][lane] = bk;
    __syncthreads();   // drains zero-fill stores (vmcnt(0) before s_barrier) + shares argmins

    // Combine halves for this row (tie -> lower k = half 0).
    const float d0 = sd[rg * 2][lane];
    const float d1 = sd[rg * 2 + 1][lane];
    const int   k0 = sk[rg * 2][lane];
    const int   k1 = sk[rg * 2 + 1][lane];
    const int   kb = (d1 < d0) ? k1 : k0;

    // Counts + one-hot scatter: half-0 wave only (one lane per row of the group).
    if (half == 0) {
        atomicAdd(&counts[kb], 1u);
        out[OFF_ENC + (size_t)g * 32768 + (size_t)lane * 512 + (size_t)kb] = 1.0f;
    }

    // Epilogue: this wave writes channels [half*32, half*32+32) for its row.
    // eq gathered from GLOBAL emb (per-lane divergent; LDS would be 64-way same-bank).
    const float* __restrict__ eq = emb + (size_t)kb * 64;
    float l0 = 0.f, l1 = 0.f, l2 = 0.f, l3 = 0.f;
    if (half == 0) {
        #pragma unroll
        for (int c = 0; c < 32; c += 4) {
            float q0 = eq[c], q1 = eq[c + 1], q2 = eq[c + 2], q3 = eq[c + 3];
            float e0 = q0 - x[c],     e1 = q1 - x[c + 1];
            float e2 = q2 - x[c + 2], e3 = q3 - x[c + 3];
            l0 += e0 * e0; l1 += e1 * e1; l2 += e2 * e2; l3 += e3 * e3;
            out[OFF_Q + inBase + (size_t)c * 4096]       = x[c]     + e0;
            out[OFF_Q + inBase + (size_t)(c + 1) * 4096] = x[c + 1] + e1;
            out[OFF_Q + inBase + (size_t)(c + 2) * 4096] = x[c + 2] + e2;
            out[OFF_Q + inBase + (size_t)(c + 3) * 4096] = x[c + 3] + e3;
        }
    } else {
        #pragma unroll
        for (int c = 32; c < 64; c += 4) {
            float q0 = eq[c], q1 = eq[c + 1], q2 = eq[c + 2], q3 = eq[c + 3];
            float e0 = q0 - x[c],     e1 = q1 - x[c + 1];
            float e2 = q2 - x[c + 2], e3 = q3 - x[c + 3];
            l0 += e0 * e0; l1 += e1 * e1; l2 += e2 * e2; l3 += e3 * e3;
            out[OFF_Q + inBase + (size_t)c * 4096]       = x[c]     + e0;
            out[OFF_Q + inBase + (size_t)(c + 1) * 4096] = x[c + 1] + e1;
            out[OFF_Q + inBase + (size_t)(c + 2) * 4096] = x[c + 2] + e2;
            out[OFF_Q + inBase + (size_t)(c + 3) * 4096] = x[c + 3] + e3;
        }
    }
    float lsum = (l0 + l1) + (l2 + l3);
    #pragma unroll
    for (int off = 32; off > 0; off >>= 1) lsum += __shfl_down(lsum, off);
    if (lane == 0) {
        unsigned long long fx = (unsigned long long)((double)lsum * 1048576.0);
        atomicAdd(lossAcc, fx);
    }
}

__global__ __launch_bounds__(512) void vq_fin(const unsigned* __restrict__ counts,
                                              const unsigned long long* __restrict__ lossAcc,
                                              float* __restrict__ out) {
    __shared__ float red[512];
    int k = threadIdx.x;
    float p = (float)counts[k] * (1.0f / 131072.0f);  // exact: count * 2^-17
    red[k] = p * logf(p + 1e-10f);
    __syncthreads();
    for (int s = 256; s > 0; s >>= 1) {
        if (k < s) red[k] += red[k + s];
        __syncthreads();
    }
    if (k == 0) {
        out[OFF_PERP] = expf(-red[0]);
        double m = ((double)(*lossAcc) / 1048576.0) / 8388608.0;
        float mf = (float)m;
        out[0] = mf + 0.25f * mf;  // q_latent + 0.25 * e_latent (identical values)
    }
}

extern "C" void kernel_launch(void* const* d_in, const int* in_sizes, int n_in,
                              void* d_out, int out_size, void* d_ws, size_t ws_size,
                              hipStream_t stream) {
    const float* in  = (const float*)d_in[0];
    // d_in[1] = labels (unused by the reference forward)
    const float* emb = (const float*)d_in[2];
    float* out = (float*)d_out;

    float* Bk                    = (float*)d_ws;                              // 512 f32
    unsigned* counts             = (unsigned*)((char*)d_ws + 2048);           // 512 u32
    unsigned long long* lossAcc  = (unsigned long long*)((char*)d_ws + 4096); // 1 u64

    vq_prep<<<1, 512, 0, stream>>>(emb, Bk, counts, lossAcc);
    vq_main<<<512, 512, 0, stream>>>(in, emb, Bk, counts, lossAcc, out);
    vq_fin<<<1, 512, 0, stream>>>(counts, lossAcc, out);
}

// Round 6
// 185.149 us; speedup vs baseline: 1.2968x; 1.2968x over previous
//
#include <hip/hip_runtime.h>

// VQ-VAE forward: N=131072 rows (D=64), K=512 codes.
// Outputs flat: [loss(1) | quantized_st(8388608, NCHW) | perplexity(1) | encodings(131072x512)]
//
// R6: outer-product VALU-GEMM restructure. R1-R5 all plateaued at ~2000cyc/code because the
// wave-uniform e-row fetch (16 ds_read_b128 or 4 s_load_dwordx16) serialized. Here each lane
// computes a 4x4 (row x code) accumulator tile: per d-step 2x ds_read_b128 feed 16 FMAs
// (issue ratio 1:8, conflict-free), no uniform-broadcast chain anywhere in the hot loop.
// Block 512 thr = 8 waves; eT[64][516] (full table transposed) + xT[64][64] in LDS (~153KB).
// Wave v owns codes [v*64,v*64+64); 8 row-groups of 64 rows sequential per block; 256 blocks.
// Zero-fill: fire-and-forget float2 stores between passes, drained by the group-end barrier
// before wave 0 scatters the one-hot 1.0s (no per-iteration store dependency).

#define OFF_Q    1
#define OFF_PERP 8388609
#define OFF_ENC  8388610
#define EPAD 516

__global__ __launch_bounds__(512) void vq_prep(const float* __restrict__ emb,
                                               float* __restrict__ Bk,
                                               unsigned* __restrict__ counts,
                                               unsigned long long* __restrict__ lossAcc) {
    int k = threadIdx.x;  // 512 threads, one per code
    const float4* e4 = reinterpret_cast<const float4*>(emb) + k * 16;
    float s = 0.f;
    #pragma unroll
    for (int i = 0; i < 16; ++i) {
        float4 v = e4[i];
        s += v.x * v.x + v.y * v.y + v.z * v.z + v.w * v.w;
    }
    Bk[k] = s;
    counts[k] = 0u;
    if (k == 0) *lossAcc = 0ull;
}

__global__ __launch_bounds__(512, 1) void vq_main(const float* __restrict__ in,
                                                  const float* __restrict__ emb,
                                                  const float* __restrict__ Bk,
                                                  unsigned* __restrict__ counts,
                                                  unsigned long long* __restrict__ lossAcc,
                                                  float* __restrict__ out) {
    __shared__ float eT[64 * EPAD];   // e transposed: eT[d][k], pad 4 -> 132096 B
    __shared__ float xT[64 * 64];     // x transposed: xT[c][row]   16384 B
    __shared__ float Bh[512];         // ||e_k||^2                   2048 B
    __shared__ float Ap[8][64];       // per-wave ||x||^2 partials   2048 B
    __shared__ float sdw[8][64];      // per-wave best dist          2048 B
    __shared__ int   skw[8][64];      // per-wave best k             2048 B

    const int tid  = (int)threadIdx.x;
    const int lane = tid & 63;
    const int v    = __builtin_amdgcn_readfirstlane(tid >> 6);  // wave 0..7 (uniform)
    const int rg   = lane >> 2;       // row-group-of-4 within tile: rows rg*4..rg*4+3
    const int cg   = lane & 3;        // code-group-of-4 selector

    // ---- stage embedding transposed into LDS (once per block) + Bh ----
    {
        const float4* emb4 = reinterpret_cast<const float4*>(emb);
        #pragma unroll
        for (int i = 0; i < 16; ++i) {
            int flat = i * 512 + tid;          // = k*16 + d4
            int k  = flat >> 4;
            int d4 = flat & 15;
            float4 ev = emb4[flat];
            eT[(d4 * 4 + 0) * EPAD + k] = ev.x;
            eT[(d4 * 4 + 1) * EPAD + k] = ev.y;
            eT[(d4 * 4 + 2) * EPAD + k] = ev.z;
            eT[(d4 * 4 + 3) * EPAD + k] = ev.w;
        }
        Bh[tid] = Bk[tid];
    }
    // (covered by group-0's barrier below)

    float lacc = 0.f;

    for (int g = 0; g < 8; ++g) {
        const int gab = (int)blockIdx.x * 8 + g;   // row-group 0..2047 = b*64+h
        const int bb  = gab >> 6;
        const int hh  = gab & 63;
        const size_t rowBase = (size_t)bb * 262144 + (size_t)hh * 64 + (size_t)lane;

        // ---- stage x tile transposed; wave v loads channels [v*8, v*8+8) ----
        float asum = 0.f;
        #pragma unroll
        for (int cc = 0; cc < 8; ++cc) {
            int c = v * 8 + cc;
            float val = in[rowBase + (size_t)c * 4096];
            xT[c * 64 + lane] = val;
            asum += val * val;
        }
        Ap[v][lane] = asum;
        __syncthreads();   // barrier1: eT (first group) + xT + Ap staged

        // ||x||^2 for my 4 rows
        float Af[4];
        #pragma unroll
        for (int i = 0; i < 4; ++i) {
            const int r = rg * 4 + i;
            float s = 0.f;
            #pragma unroll
            for (int vv = 0; vv < 8; ++vv) s += Ap[vv][r];
            Af[i] = s;
        }

        float bd[4] = {3.4e38f, 3.4e38f, 3.4e38f, 3.4e38f};
        int   bk[4] = {0, 0, 0, 0};
        float2* zb = reinterpret_cast<float2*>(out + OFF_ENC + (size_t)gab * 32768);

        #pragma unroll
        for (int p = 0; p < 4; ++p) {
            const int kb0 = v * 64 + p * 16 + cg * 4;   // my 4 codes this pass
            const float4 bkv = *reinterpret_cast<const float4*>(&Bh[kb0]);
            const float* xp = &xT[rg * 4];
            const float* ep = &eT[kb0];

            float a00 = 0.f, a01 = 0.f, a02 = 0.f, a03 = 0.f;
            float a10 = 0.f, a11 = 0.f, a12 = 0.f, a13 = 0.f;
            float a20 = 0.f, a21 = 0.f, a22 = 0.f, a23 = 0.f;
            float a30 = 0.f, a31 = 0.f, a32 = 0.f, a33 = 0.f;

            #pragma unroll 8
            for (int d = 0; d < 64; ++d) {
                const float4 xf = *reinterpret_cast<const float4*>(xp + (size_t)d * 64);
                const float4 ef = *reinterpret_cast<const float4*>(ep + (size_t)d * EPAD);
                a00 += xf.x * ef.x; a01 += xf.x * ef.y; a02 += xf.x * ef.z; a03 += xf.x * ef.w;
                a10 += xf.y * ef.x; a11 += xf.y * ef.y; a12 += xf.y * ef.z; a13 += xf.y * ef.w;
                a20 += xf.z * ef.x; a21 += xf.z * ef.y; a22 += xf.z * ef.z; a23 += xf.z * ef.w;
                a30 += xf.w * ef.x; a31 += xf.w * ef.y; a32 += xf.w * ef.z; a33 += xf.w * ef.w;
            }

            // fire-and-forget zero-fill slice (8 float2 = 64B/thread/pass); no waits here
            const float2 z2 = make_float2(0.f, 0.f);
            #pragma unroll
            for (int z = 0; z < 8; ++z) zb[tid * 32 + p * 8 + z] = z2;

            // dist + argmin update (k ascending: pass-major, j-minor => first-min tie rule)
            #pragma unroll
            for (int j = 0; j < 4; ++j) {
                const float Bj = (j == 0) ? bkv.x : (j == 1) ? bkv.y : (j == 2) ? bkv.z : bkv.w;
                const int k = kb0 + j;
                float di;
                di = (Af[0] + Bj) - 2.0f * ((j == 0) ? a00 : (j == 1) ? a01 : (j == 2) ? a02 : a03);
                if (di < bd[0]) { bd[0] = di; bk[0] = k; }
                di = (Af[1] + Bj) - 2.0f * ((j == 0) ? a10 : (j == 1) ? a11 : (j == 2) ? a12 : a13);
                if (di < bd[1]) { bd[1] = di; bk[1] = k; }
                di = (Af[2] + Bj) - 2.0f * ((j == 0) ? a20 : (j == 1) ? a21 : (j == 2) ? a22 : a23);
                if (di < bd[2]) { bd[2] = di; bk[2] = k; }
                di = (Af[3] + Bj) - 2.0f * ((j == 0) ? a30 : (j == 1) ? a31 : (j == 2) ? a32 : a33);
                if (di < bd[3]) { bd[3] = di; bk[3] = k; }
            }
        }

        // combine across the 4 cg lanes of each quad (equal dist -> lower k)
        #pragma unroll
        for (int i = 0; i < 4; ++i) {
            #pragma unroll
            for (int s = 1; s <= 2; s <<= 1) {
                float od = __shfl_xor(bd[i], s);
                int   ok = __shfl_xor(bk[i], s);
                if (od < bd[i] || (od == bd[i] && ok < bk[i])) { bd[i] = od; bk[i] = ok; }
            }
        }
        // lane l carries row l: pick i = cg (static-index select)
        const float myd = (cg == 0) ? bd[0] : (cg == 1) ? bd[1] : (cg == 2) ? bd[2] : bd[3];
        const int   myk = (cg == 0) ? bk[0] : (cg == 1) ? bk[1] : (cg == 2) ? bk[2] : bk[3];
        sdw[v][lane] = myd;
        skw[v][lane] = myk;
        __syncthreads();   // barrier2

        // final argmin across waves (v ascending == k-range ascending; strict < => lowest k)
        float fd = sdw[0][lane];
        int   fk = skw[0][lane];
        #pragma unroll
        for (int vv = 1; vv < 8; ++vv) {
            const float dv = sdw[vv][lane];
            const int   kv = skw[vv][lane];
            if (dv < fd) { fd = dv; fk = kv; }
        }

        // epilogue: wave v writes channels [v*8, v*8+8) for all 64 rows (lane = row)
        #pragma unroll
        for (int cc = 0; cc < 8; ++cc) {
            const int c = v * 8 + cc;
            const float xv = xT[c * 64 + lane];
            const float q  = eT[c * EPAD + fk];
            const float dd = q - xv;
            lacc += dd * dd;
            out[OFF_Q + rowBase + (size_t)c * 4096] = xv + dd;   // x + (q - x), ref order
        }
        __syncthreads();   // barrier3: protects xT for next group AND drains this group's
                           // zero-fill stores (vmcnt(0) before s_barrier) => scatter is safe

        if (v == 0) {
            atomicAdd(&counts[fk], 1u);
            out[OFF_ENC + (size_t)gab * 32768 + (size_t)lane * 512 + (size_t)fk] = 1.0f;
        }
    }

    // deterministic loss accumulation (fixed-point, validated R1-R5)
    #pragma unroll
    for (int off = 32; off > 0; off >>= 1) lacc += __shfl_down(lacc, off);
    if (lane == 0) {
        unsigned long long fx = (unsigned long long)((double)lacc * 1048576.0);
        atomicAdd(lossAcc, fx);
    }
}

__global__ __launch_bounds__(512) void vq_fin(const unsigned* __restrict__ counts,
                                              const unsigned long long* __restrict__ lossAcc,
                                              float* __restrict__ out) {
    __shared__ float red[512];
    int k = threadIdx.x;
    float p = (float)counts[k] * (1.0f / 131072.0f);  // exact: count * 2^-17
    red[k] = p * logf(p + 1e-10f);
    __syncthreads();
    for (int s = 256; s > 0; s >>= 1) {
        if (k < s) red[k] += red[k + s];
        __syncthreads();
    }
    if (k == 0) {
        out[OFF_PERP] = expf(-red[0]);
        double m = ((double)(*lossAcc) / 1048576.0) / 8388608.0;
        float mf = (float)m;
        out[0] = mf + 0.25f * mf;  // q_latent + 0.25 * e_latent (identical values)
    }
}

extern "C" void kernel_launch(void* const* d_in, const int* in_sizes, int n_in,
                              void* d_out, int out_size, void* d_ws, size_t ws_size,
                              hipStream_t stream) {
    const float* in  = (const float*)d_in[0];
    // d_in[1] = labels (unused by the reference forward)
    const float* emb = (const float*)d_in[2];
    float* out = (float*)d_out;

    float* Bk                    = (float*)d_ws;                              // 512 f32
    unsigned* counts             = (unsigned*)((char*)d_ws + 2048);           // 512 u32
    unsigned long long* lossAcc  = (unsigned long long*)((char*)d_ws + 4096); // 1 u64

    vq_prep<<<1, 512, 0, stream>>>(emb, Bk, counts, lossAcc);
    vq_main<<<256, 512, 0, stream>>>(in, emb, Bk, counts, lossAcc, out);
    vq_fin<<<1, 512, 0, stream>>>(counts, lossAcc, out);
}